// Round 1
// baseline (203.100 us; speedup 1.0000x reference)
//
#include <hip/hip_runtime.h>
#include <hip/hip_bf16.h>

#define BS 64          // rotation block size
#define RBLOCKS 64     // number of rotation blocks
#define NELEM 2016     // strict upper triangle elements
#define D 4096         // feature dim = RBLOCKS * BS

// ---------------------------------------------------------------------------
// Kernel A: build R[r] = I + 2Q + 2Q^2 + 2Q^3 + 2Q^4 per block (fp32, exact
// reference math). One workgroup per rotation block. Q kept in LDS; each
// thread owns column j = tid&63 and rows ibase..ibase+15, with Q's column j
// cached in registers so every matmul is 1 broadcast LDS read + FMA per MAC.
// ---------------------------------------------------------------------------
__global__ __launch_bounds__(256) void rot_kernel(const float* __restrict__ w,
                                                  float* __restrict__ Rout) {
    const int blk = blockIdx.x;
    __shared__ float Q [BS * BS];
    __shared__ float B0[BS * BS];
    __shared__ float B1[BS * BS];
    const int t = threadIdx.x;
    const float* wb = w + blk * NELEM;

    // Build skew-symmetric Q from strict upper-triangle vector.
    for (int e = t; e < BS * BS; e += 256) {
        const int i = e >> 6, j = e & 63;
        float v = 0.f;
        if (i < j)      v =  wb[63 * i - (i * (i - 1)) / 2 + (j - i - 1)];
        else if (i > j) v = -wb[63 * j - (j * (j - 1)) / 2 + (i - j - 1)];
        Q[e] = v;
    }
    __syncthreads();

    const int j     = t & 63;
    const int ibase = (t >> 6) << 4;

    // Cache Q's column j in registers (reused by all 3 matmuls).
    float qcol[BS];
#pragma unroll
    for (int k = 0; k < BS; ++k) qcol[k] = Q[k * BS + j];

    // racc = I + 2Q for this thread's 16 elements.
    float racc[16];
#pragma unroll
    for (int s = 0; s < 16; ++s) {
        const int i = ibase + s;
        racc[s] = (i == j ? 1.f : 0.f) + 2.f * Q[i * BS + j];
    }

    // Three sequential matmuls: Q^2, Q^3, Q^4, each accumulated with weight 2.
    const float* P = Q;
    float*       T = B0;
    for (int pass = 0; pass < 3; ++pass) {
#pragma unroll
        for (int s = 0; s < 16; ++s) {
            const int i = ibase + s;
            float sum = 0.f;
#pragma unroll
            for (int k = 0; k < BS; ++k) sum += P[i * BS + k] * qcol[k];
            T[i * BS + j] = sum;
            racc[s] += 2.f * sum;
        }
        __syncthreads();
        P = T;
        T = (pass == 0) ? B1 : B0;
    }

    // Store R row-major: Rout[blk][i][j]
#pragma unroll
    for (int s = 0; s < 16; ++s) {
        const int i = ibase + s;
        Rout[blk * (BS * BS) + i * BS + j] = racc[s];
    }
}

// ---------------------------------------------------------------------------
// Kernel B: y[row, rblk*64 + c] = sum_k x[row, rblk*64 + k] * R[rblk][k][c]
// Grid: (M/64) * 64 blocks; block = 64 rows x one rblk. 256 threads.
// X tile in LDS (stride 65 -> 2-way bank aliasing = free); R tile in LDS
// (stride 64; all compute reads are wave-uniform broadcasts = conflict-free).
// Thread = (row = tid&63, 16 consecutive output columns).
// ---------------------------------------------------------------------------
__global__ __launch_bounds__(256) void apply_kernel(const float* __restrict__ x,
                                                    const float* __restrict__ R,
                                                    float* __restrict__ y) {
    const int bid  = blockIdx.x;
    const int rblk = bid & 63;
    const int mblk = bid >> 6;
    const int t    = threadIdx.x;

    __shared__ float Xs[BS * 65];
    __shared__ float Rs[BS * BS];

    const long mbase = (long)mblk * BS;
    const float* xb = x + mbase * D + rblk * BS;
    const float* rb = R + rblk * (BS * BS);

    // Stage X tile: 64 rows x 64 cols, coalesced float4 loads.
#pragma unroll
    for (int p = 0; p < 4; ++p) {
        const int idx = p * 256 + t;
        const int row = idx >> 4;   // 0..63
        const int c4  = idx & 15;   // 0..15
        const float4 v = *reinterpret_cast<const float4*>(xb + (long)row * D + c4 * 4);
        float* d = &Xs[row * 65 + c4 * 4];
        d[0] = v.x; d[1] = v.y; d[2] = v.z; d[3] = v.w;
    }
    // Stage R tile (L2-resident; 16 KB).
#pragma unroll
    for (int p = 0; p < 4; ++p) {
        const int idx = p * 256 + t;
        const int k   = idx >> 4;
        const int c4  = idx & 15;
        const float4 v = *reinterpret_cast<const float4*>(rb + k * BS + c4 * 4);
        *reinterpret_cast<float4*>(&Rs[k * BS + c4 * 4]) = v;
    }
    __syncthreads();

    const int row = t & 63;
    const int c0  = (t >> 6) << 4;   // wave-uniform: 0,16,32,48

    float acc[16];
#pragma unroll
    for (int s = 0; s < 16; ++s) acc[s] = 0.f;

    const float* xrow = &Xs[row * 65];

#pragma unroll 4
    for (int k = 0; k < BS; ++k) {
        const float xv = xrow[k];
        const float4 r0 = *reinterpret_cast<const float4*>(&Rs[k * BS + c0     ]);
        const float4 r1 = *reinterpret_cast<const float4*>(&Rs[k * BS + c0 +  4]);
        const float4 r2 = *reinterpret_cast<const float4*>(&Rs[k * BS + c0 +  8]);
        const float4 r3 = *reinterpret_cast<const float4*>(&Rs[k * BS + c0 + 12]);
        acc[ 0] += xv * r0.x; acc[ 1] += xv * r0.y; acc[ 2] += xv * r0.z; acc[ 3] += xv * r0.w;
        acc[ 4] += xv * r1.x; acc[ 5] += xv * r1.y; acc[ 6] += xv * r1.z; acc[ 7] += xv * r1.w;
        acc[ 8] += xv * r2.x; acc[ 9] += xv * r2.y; acc[10] += xv * r2.z; acc[11] += xv * r2.w;
        acc[12] += xv * r3.x; acc[13] += xv * r3.y; acc[14] += xv * r3.z; acc[15] += xv * r3.w;
    }

    float* yb = y + (mbase + row) * D + rblk * BS + c0;
#pragma unroll
    for (int q = 0; q < 4; ++q) {
        float4 v;
        v.x = acc[q * 4 + 0]; v.y = acc[q * 4 + 1];
        v.z = acc[q * 4 + 2]; v.w = acc[q * 4 + 3];
        *reinterpret_cast<float4*>(yb + q * 4) = v;
    }
}

extern "C" void kernel_launch(void* const* d_in, const int* in_sizes, int n_in,
                              void* d_out, int out_size, void* d_ws, size_t ws_size,
                              hipStream_t stream) {
    (void)in_sizes; (void)n_in; (void)out_size; (void)ws_size;
    const float* x = (const float*)d_in[0];
    const float* w = (const float*)d_in[1];
    float* y = (float*)d_out;
    float* R = (float*)d_ws;   // 64 * 64 * 64 * 4 B = 1 MB

    rot_kernel<<<RBLOCKS, 256, 0, stream>>>(w, R);

    const int M = 4 * 4096;                 // rows
    const int nblocks = (M / BS) * RBLOCKS; // 256 * 64 = 16384
    apply_kernel<<<nblocks, 256, 0, stream>>>(x, R, y);
}